// Round 4
// baseline (39030.606 us; speedup 1.0000x reference)
//
#include <hip/hip_runtime.h>
#include <hip/hip_bf16.h>

// ---------------------------------------------------------------------------
// HierarchicalGRU on MI355X — compensated double-bf16 MFMA, regular launch.
// 8 groups (g=blockIdx&7) x 32 CUs; group owns 32 batch rows; CU m owns
// hidden cols [m*16, m*16+16). Every GEMM operand (weights, states) is a
// (hi,lo) bf16 pair: v = hi + lo, |err| <= 2^-17|v|. Each logical GEMM =
// 3 MFMA products (ah*bh + ah*bl + al*bh), fp32 accumulation, fp32 LDS
// masters, fp32 head. Whh/Wip/Whp hi+lo VGPR-resident; Wih / Pin stream
// from L2 (only touched once per 4-step chunk).
// R4 change: NO hipLaunchCooperativeKernel (R2/R3 showed it silently no-ops
// in this harness: absmax was bit-identical across different numerics ==
// output was all-zeros == hgru_main never ran). Plain <<<256,256>>> launch;
// all 256 blocks are co-resident (1/CU) so the atomic spin barrier is safe.
// Static LDS ~61KB (<64KB default cap), no dynamic smem, no FuncSetAttribute.
// ---------------------------------------------------------------------------

#define B_   256
#define S_   512
#define E_   256
#define HW_  512
#define STATE_STRIDE (B_ * HW_)

typedef __attribute__((ext_vector_type(8))) short bf16x8;
typedef __attribute__((ext_vector_type(4))) float f32x4;

__device__ __forceinline__ float sigm(float x) { return 1.f / (1.f + __expf(-x)); }
__device__ __forceinline__ float tanh_f(float x) { float e = __expf(2.f * x); return (e - 1.f) / (e + 1.f); }

__device__ __forceinline__ f32x4 mfma16(bf16x8 a, bf16x8 b, f32x4 c) {
  return __builtin_amdgcn_mfma_f32_16x16x32_bf16(a, b, c, 0, 0, 0);
}
#define MFMA3(ACC, AH, AL, BH, BL)  \
  ACC = mfma16(AH, BH, ACC);        \
  ACC = mfma16(AH, BL, ACC);        \
  ACC = mfma16(AL, BH, ACC);

__device__ __forceinline__ void store_pair(__hip_bfloat16* hi, __hip_bfloat16* lo,
                                           long idx, float v) {
  __hip_bfloat16 h = __float2bfloat16(v);
  hi[idx] = h;
  lo[idx] = __float2bfloat16(v - __bfloat162float(h));
}

// Intra-group barrier (32 blocks), device-scope atomics. Needs co-residency
// only (all 256 blocks fit at 1/CU); no cooperative API.
__device__ __forceinline__ void grp_barrier(unsigned* cnt, unsigned target) {
  __threadfence();
  __syncthreads();
  if (threadIdx.x == 0) {
    __hip_atomic_fetch_add(cnt, 1u, __ATOMIC_RELEASE, __HIP_MEMORY_SCOPE_AGENT);
    while (__hip_atomic_load(cnt, __ATOMIC_ACQUIRE, __HIP_MEMORY_SCOPE_AGENT) < target)
      __builtin_amdgcn_s_sleep(1);
  }
  __syncthreads();
  __threadfence();
}

__global__ void split_hilo(const float* __restrict__ s,
                           __hip_bfloat16* __restrict__ hi,
                           __hip_bfloat16* __restrict__ lo, int n) {
  int i = blockIdx.x * blockDim.x + threadIdx.x;
  int st = gridDim.x * blockDim.x;
  for (; i < n; i += st) {
    float v = s[i];
    __hip_bfloat16 h = __float2bfloat16(v);
    hi[i] = h;
    lo[i] = __float2bfloat16(v - __bfloat162float(h));
  }
}

__global__ __launch_bounds__(256, 1) void hgru_main(
    const int* __restrict__ ids, const int* __restrict__ lens,
    const float* __restrict__ emb,
    const float* __restrict__ b_ih_w, const float* __restrict__ b_hh_w,
    const float* __restrict__ pin_b,
    const float* __restrict__ b_ih_p, const float* __restrict__ b_hh_p,
    const __hip_bfloat16* __restrict__ WihHi, const __hip_bfloat16* __restrict__ WihLo,
    const __hip_bfloat16* __restrict__ WhhHi, const __hip_bfloat16* __restrict__ WhhLo,
    const __hip_bfloat16* __restrict__ PinHi, const __hip_bfloat16* __restrict__ PinLo,
    const __hip_bfloat16* __restrict__ WipHi, const __hip_bfloat16* __restrict__ WipLo,
    const __hip_bfloat16* __restrict__ WhpHi, const __hip_bfloat16* __restrict__ WhpLo,
    __hip_bfloat16* hwHi, __hip_bfloat16* hwLo,     // 2 x [256][512] ping-pong each
    __hip_bfloat16* hpHi, __hip_bfloat16* hpLo,     // 2 x [256][512] ping-pong each
    __hip_bfloat16* pinHi, __hip_bfloat16* pinLo,   // [256][512]
    float* hw_f, float* hp_f,
    unsigned* counters)
{
  const int tid = threadIdx.x;
  const int g = blockIdx.x & 7;
  const int m = blockIdx.x >> 3;
  const int w = tid >> 6;
  const int l = tid & 63;
  const int lrow = l & 15;
  const int lk8 = (l >> 4) * 8;
  const int r0 = g * 32;
  const int hc0 = m * 16;
  unsigned* cnt = counters + g * 64;
  unsigned bar = 0;

  __shared__ float red[4][6][16][16];    // per-wave partial tiles
  __shared__ float gib[4][32][48];       // gi_base for current 4-step chunk
  __shared__ float giP[32][48];          // planner gi staging
  __shared__ float hwm[32][16];          // fp32 master, own cols
  __shared__ float hpm[32][16];
  __shared__ float bhh_s[48], bihw_s[48], bihp_s[48], bhhp_s[48], pinb_s[16];
  __shared__ int len_s[32];
  __shared__ int ids_s[32][4];

  if (tid < 48) {
    int gcol = (tid >> 4) * 512 + hc0 + (tid & 15);
    bhh_s[tid]  = b_hh_w[gcol];
    bihw_s[tid] = b_ih_w[gcol];
    bihp_s[tid] = b_ih_p[gcol];
    bhhp_s[tid] = b_hh_p[gcol];
  }
  if (tid < 16) pinb_s[tid] = pin_b[hc0 + tid];
  if (tid < 32) len_s[tid] = lens[r0 + tid];
  {
    int o = tid * 2;
    hwm[o >> 4][o & 15] = 0.f; hpm[o >> 4][o & 15] = 0.f;
    o++;
    hwm[o >> 4][o & 15] = 0.f; hpm[o >> 4][o & 15] = 0.f;
  }
  __syncthreads();

  // ---- VGPR-resident hi/lo weight fragments (per-wave K-slice of 128) ----
  bf16x8 whh_h[3][4], whh_l[3][4], wip_h[3][4], wip_l[3][4], whp_h[3][4], whp_l[3][4];
#pragma unroll
  for (int nt = 0; nt < 3; ++nt)
#pragma unroll
    for (int kt = 0; kt < 4; ++kt) {
      long o = (long)(nt * 512 + hc0 + lrow) * 512 + w * 128 + kt * 32 + lk8;
      whh_h[nt][kt] = *(const bf16x8*)(WhhHi + o);
      whh_l[nt][kt] = *(const bf16x8*)(WhhLo + o);
      wip_h[nt][kt] = *(const bf16x8*)(WipHi + o);
      wip_l[nt][kt] = *(const bf16x8*)(WipLo + o);
      whp_h[nt][kt] = *(const bf16x8*)(WhpHi + o);
      whp_l[nt][kt] = *(const bf16x8*)(WhpLo + o);
    }

  // ---- helper: rebuild gi_base for chunk [tbase, tbase+4) from hp pair ----
  auto build_gi = [&](int tbase, const __hip_bfloat16* hpH, const __hip_bfloat16* hpL) {
    if (tid < 128) {
      int r = tid >> 2, tp = tid & 3;
      ids_s[r][tp] = ids[(r0 + r) * S_ + tbase + tp];
    }
    // hp-part: [32,512](pair) @ Wih_hp^T(pair, streamed from L2) -> [32,48]
    bf16x8 ah[2][4], al[2][4];
#pragma unroll
    for (int mt = 0; mt < 2; ++mt)
#pragma unroll
      for (int kt = 0; kt < 4; ++kt) {
        long o = (long)(r0 + mt * 16 + lrow) * 512 + w * 128 + kt * 32 + lk8;
        ah[mt][kt] = *(const bf16x8*)(hpH + o);
        al[mt][kt] = *(const bf16x8*)(hpL + o);
      }
    f32x4 acc[6];
#pragma unroll
    for (int i = 0; i < 6; ++i) acc[i] = 0.f;
#pragma unroll
    for (int nt = 0; nt < 3; ++nt)
#pragma unroll
      for (int kt = 0; kt < 4; ++kt) {
        long o = (long)(nt * 512 + hc0 + lrow) * 768 + 256 + w * 128 + kt * 32 + lk8;
        bf16x8 bh = *(const bf16x8*)(WihHi + o);
        bf16x8 bl = *(const bf16x8*)(WihLo + o);
        MFMA3(acc[0 * 3 + nt], ah[0][kt], al[0][kt], bh, bl);
        MFMA3(acc[1 * 3 + nt], ah[1][kt], al[1][kt], bh, bl);
      }
#pragma unroll
    for (int tile = 0; tile < 6; ++tile)
#pragma unroll
      for (int r = 0; r < 4; ++r)
        red[w][tile][(l >> 4) * 4 + r][l & 15] = acc[tile][r];
    __syncthreads();
#pragma unroll
    for (int q = 0; q < 6; ++q) {
      int o = q * 256 + tid;
      int b = o / 48, c = o - b * 48;
      int tile = (b >> 4) * 3 + (c >> 4);
      float v = red[0][tile][b & 15][c & 15] + red[1][tile][b & 15][c & 15] +
                red[2][tile][b & 15][c & 15] + red[3][tile][b & 15][c & 15];
      v += bihw_s[c];
      gib[0][b][c] = v; gib[1][b][c] = v; gib[2][b][c] = v; gib[3][b][c] = v;
    }
    __syncthreads();
    // x-part: per t', [32,256](emb hi/lo split on the fly) @ Wih_x^T(pair)
    bf16x8 bxh[3][2], bxl[3][2];
#pragma unroll
    for (int nt = 0; nt < 3; ++nt)
#pragma unroll
      for (int kt = 0; kt < 2; ++kt) {
        long o = (long)(nt * 512 + hc0 + lrow) * 768 + w * 64 + kt * 32 + lk8;
        bxh[nt][kt] = *(const bf16x8*)(WihHi + o);
        bxl[nt][kt] = *(const bf16x8*)(WihLo + o);
      }
    for (int tp = 0; tp < 4; ++tp) {
      bf16x8 axh[2][2], axl[2][2];
#pragma unroll
      for (int mt = 0; mt < 2; ++mt) {
        int id = ids_s[mt * 16 + lrow][tp];
        const float* ep = emb + (long)id * E_ + w * 64 + lk8;
#pragma unroll
        for (int kt = 0; kt < 2; ++kt) {
          float4 e0 = *reinterpret_cast<const float4*>(ep + kt * 32);
          float4 e1 = *reinterpret_cast<const float4*>(ep + kt * 32 + 4);
          float ef[8] = {e0.x, e0.y, e0.z, e0.w, e1.x, e1.y, e1.z, e1.w};
          bf16x8 vh, vl;
#pragma unroll
          for (int j = 0; j < 8; ++j) {
            __hip_bfloat16 hb = __float2bfloat16(ef[j]);
            __hip_bfloat16 lb = __float2bfloat16(ef[j] - __bfloat162float(hb));
            vh[j] = *reinterpret_cast<short*>(&hb);
            vl[j] = *reinterpret_cast<short*>(&lb);
          }
          axh[mt][kt] = vh; axl[mt][kt] = vl;
        }
      }
      f32x4 a2[6];
#pragma unroll
      for (int i = 0; i < 6; ++i) a2[i] = 0.f;
#pragma unroll
      for (int nt = 0; nt < 3; ++nt)
#pragma unroll
        for (int kt = 0; kt < 2; ++kt) {
          MFMA3(a2[0 * 3 + nt], axh[0][kt], axl[0][kt], bxh[nt][kt], bxl[nt][kt]);
          MFMA3(a2[1 * 3 + nt], axh[1][kt], axl[1][kt], bxh[nt][kt], bxl[nt][kt]);
        }
#pragma unroll
      for (int tile = 0; tile < 6; ++tile)
#pragma unroll
        for (int r = 0; r < 4; ++r)
          red[w][tile][(l >> 4) * 4 + r][l & 15] = a2[tile][r];
      __syncthreads();
#pragma unroll
      for (int q = 0; q < 6; ++q) {
        int o = q * 256 + tid;
        int b = o / 48, c = o - b * 48;
        int tile = (b >> 4) * 3 + (c >> 4);
        gib[tp][b][c] += red[0][tile][b & 15][c & 15] + red[1][tile][b & 15][c & 15] +
                         red[2][tile][b & 15][c & 15] + red[3][tile][b & 15][c & 15];
      }
      __syncthreads();
    }
  };

  build_gi(0, hpHi, hpLo);   // hp == 0 initially (buffers zeroed by memset)

#pragma unroll 1
  for (int t = 0; t < S_; ++t) {
    // ---------------- worker step ----------------
    {
      const __hip_bfloat16* hrH = hwHi + (t & 1) * STATE_STRIDE;
      const __hip_bfloat16* hrL = hwLo + (t & 1) * STATE_STRIDE;
      __hip_bfloat16* hwpH = hwHi + ((t & 1) ^ 1) * STATE_STRIDE;
      __hip_bfloat16* hwpL = hwLo + ((t & 1) ^ 1) * STATE_STRIDE;
      bf16x8 ah[2][4], al[2][4];
#pragma unroll
      for (int mt = 0; mt < 2; ++mt)
#pragma unroll
        for (int kt = 0; kt < 4; ++kt) {
          long o = (long)(r0 + mt * 16 + lrow) * 512 + w * 128 + kt * 32 + lk8;
          ah[mt][kt] = *(const bf16x8*)(hrH + o);
          al[mt][kt] = *(const bf16x8*)(hrL + o);
        }
      f32x4 acc[6];
#pragma unroll
      for (int i = 0; i < 6; ++i) acc[i] = 0.f;
#pragma unroll
      for (int kt = 0; kt < 4; ++kt)
#pragma unroll
        for (int nt = 0; nt < 3; ++nt) {
          MFMA3(acc[0 * 3 + nt], ah[0][kt], al[0][kt], whh_h[nt][kt], whh_l[nt][kt]);
          MFMA3(acc[1 * 3 + nt], ah[1][kt], al[1][kt], whh_h[nt][kt], whh_l[nt][kt]);
        }
#pragma unroll
      for (int tile = 0; tile < 6; ++tile)
#pragma unroll
        for (int r = 0; r < 4; ++r)
          red[w][tile][(l >> 4) * 4 + r][l & 15] = acc[tile][r];
      __syncthreads();
      int tc = t & 3;
#pragma unroll
      for (int q = 0; q < 2; ++q) {
        int o = tid * 2 + q;
        int b = o >> 4, j = o & 15, mt = b >> 4, rr = b & 15;
        float gr = red[0][mt * 3 + 0][rr][j] + red[1][mt * 3 + 0][rr][j] +
                   red[2][mt * 3 + 0][rr][j] + red[3][mt * 3 + 0][rr][j] + bhh_s[j];
        float gz = red[0][mt * 3 + 1][rr][j] + red[1][mt * 3 + 1][rr][j] +
                   red[2][mt * 3 + 1][rr][j] + red[3][mt * 3 + 1][rr][j] + bhh_s[16 + j];
        float gn = red[0][mt * 3 + 2][rr][j] + red[1][mt * 3 + 2][rr][j] +
                   red[2][mt * 3 + 2][rr][j] + red[3][mt * 3 + 2][rr][j] + bhh_s[32 + j];
        float rg = sigm(gib[tc][b][j] + gr);
        float zg = sigm(gib[tc][b][16 + j] + gz);
        float ng = tanh_f(gib[tc][b][32 + j] + rg * gn);
        float h = hwm[b][j];
        float hn2 = (t < len_s[b]) ? ((1.f - zg) * ng + zg * h) : h;
        hwm[b][j] = hn2;
        store_pair(hwpH, hwpL, (long)(r0 + b) * 512 + hc0 + j, hn2);
      }
      grp_barrier(cnt, 32u * (++bar));
    }

    // ---------------- planner (every 4th step) ----------------
    if (((t + 1) & 3) == 0) {
      const __hip_bfloat16* hrH = hwHi + ((t & 1) ^ 1) * STATE_STRIDE;  // post-update hw
      const __hip_bfloat16* hrL = hwLo + ((t & 1) ^ 1) * STATE_STRIDE;
      int c = t >> 2;
      const __hip_bfloat16* hprH = hpHi + (c & 1) * STATE_STRIDE;
      const __hip_bfloat16* hprL = hpLo + (c & 1) * STATE_STRIDE;
      __hip_bfloat16* hpwH = hpHi + ((c & 1) ^ 1) * STATE_STRIDE;
      __hip_bfloat16* hpwL = hpLo + ((c & 1) ^ 1) * STATE_STRIDE;

      // pin = hw @ pin_w.T + pin_b (own 16 cols); Pin streamed from L2
      {
        bf16x8 ah[2][4], al[2][4];
#pragma unroll
        for (int mt = 0; mt < 2; ++mt)
#pragma unroll
          for (int kt = 0; kt < 4; ++kt) {
            long o = (long)(r0 + mt * 16 + lrow) * 512 + w * 128 + kt * 32 + lk8;
            ah[mt][kt] = *(const bf16x8*)(hrH + o);
            al[mt][kt] = *(const bf16x8*)(hrL + o);
          }
        f32x4 pa[2];
        pa[0] = 0.f; pa[1] = 0.f;
#pragma unroll
        for (int kt = 0; kt < 4; ++kt) {
          long o = (long)(hc0 + lrow) * 512 + w * 128 + kt * 32 + lk8;
          bf16x8 bnh = *(const bf16x8*)(PinHi + o);
          bf16x8 bnl = *(const bf16x8*)(PinLo + o);
          MFMA3(pa[0], ah[0][kt], al[0][kt], bnh, bnl);
          MFMA3(pa[1], ah[1][kt], al[1][kt], bnh, bnl);
        }
#pragma unroll
        for (int mt = 0; mt < 2; ++mt)
#pragma unroll
          for (int r = 0; r < 4; ++r)
            red[w][mt][(l >> 4) * 4 + r][l & 15] = pa[mt][r];
        __syncthreads();
#pragma unroll
        for (int q = 0; q < 2; ++q) {
          int o = tid * 2 + q;
          int b = o >> 4, j = o & 15;
          float v = red[0][b >> 4][b & 15][j] + red[1][b >> 4][b & 15][j] +
                    red[2][b >> 4][b & 15][j] + red[3][b >> 4][b & 15][j] + pinb_s[j];
          store_pair(pinHi, pinLo, (long)(r0 + b) * 512 + hc0 + j, v);
        }
        grp_barrier(cnt, 32u * (++bar));
      }

      // planner GRU gates
      {
        bf16x8 ah[2][4], al[2][4];
#pragma unroll
        for (int mt = 0; mt < 2; ++mt)
#pragma unroll
          for (int kt = 0; kt < 4; ++kt) {
            long o = (long)(r0 + mt * 16 + lrow) * 512 + w * 128 + kt * 32 + lk8;
            ah[mt][kt] = *(const bf16x8*)(pinHi + o);
            al[mt][kt] = *(const bf16x8*)(pinLo + o);
          }
        f32x4 acc[6];
#pragma unroll
        for (int i = 0; i < 6; ++i) acc[i] = 0.f;
#pragma unroll
        for (int nt = 0; nt < 3; ++nt)
#pragma unroll
          for (int kt = 0; kt < 4; ++kt) {
            MFMA3(acc[0 * 3 + nt], ah[0][kt], al[0][kt], wip_h[nt][kt], wip_l[nt][kt]);
            MFMA3(acc[1 * 3 + nt], ah[1][kt], al[1][kt], wip_h[nt][kt], wip_l[nt][kt]);
          }
#pragma unroll
        for (int tile = 0; tile < 6; ++tile)
#pragma unroll
          for (int r = 0; r < 4; ++r)
            red[w][tile][(l >> 4) * 4 + r][l & 15] = acc[tile][r];
        __syncthreads();
#pragma unroll
        for (int q = 0; q < 6; ++q) {
          int o = q * 256 + tid;
          int b = o / 48, cc = o - b * 48;
          int tile = (b >> 4) * 3 + (cc >> 4);
          giP[b][cc] = red[0][tile][b & 15][cc & 15] + red[1][tile][b & 15][cc & 15] +
                       red[2][tile][b & 15][cc & 15] + red[3][tile][b & 15][cc & 15] +
                       bihp_s[cc];
        }
        __syncthreads();
        // gh_p = hp @ w_hh_p.T + b_hh_p
#pragma unroll
        for (int mt = 0; mt < 2; ++mt)
#pragma unroll
          for (int kt = 0; kt < 4; ++kt) {
            long o = (long)(r0 + mt * 16 + lrow) * 512 + w * 128 + kt * 32 + lk8;
            ah[mt][kt] = *(const bf16x8*)(hprH + o);
            al[mt][kt] = *(const bf16x8*)(hprL + o);
          }
#pragma unroll
        for (int i = 0; i < 6; ++i) acc[i] = 0.f;
#pragma unroll
        for (int nt = 0; nt < 3; ++nt)
#pragma unroll
          for (int kt = 0; kt < 4; ++kt) {
            MFMA3(acc[0 * 3 + nt], ah[0][kt], al[0][kt], whp_h[nt][kt], whp_l[nt][kt]);
            MFMA3(acc[1 * 3 + nt], ah[1][kt], al[1][kt], whp_h[nt][kt], whp_l[nt][kt]);
          }
#pragma unroll
        for (int tile = 0; tile < 6; ++tile)
#pragma unroll
          for (int r = 0; r < 4; ++r)
            red[w][tile][(l >> 4) * 4 + r][l & 15] = acc[tile][r];
        __syncthreads();
#pragma unroll
        for (int q = 0; q < 2; ++q) {
          int o = tid * 2 + q;
          int b = o >> 4, j = o & 15, mt = b >> 4, rr = b & 15;
          float gr = red[0][mt * 3 + 0][rr][j] + red[1][mt * 3 + 0][rr][j] +
                     red[2][mt * 3 + 0][rr][j] + red[3][mt * 3 + 0][rr][j] + bhhp_s[j];
          float gz = red[0][mt * 3 + 1][rr][j] + red[1][mt * 3 + 1][rr][j] +
                     red[2][mt * 3 + 1][rr][j] + red[3][mt * 3 + 1][rr][j] + bhhp_s[16 + j];
          float gn = red[0][mt * 3 + 2][rr][j] + red[1][mt * 3 + 2][rr][j] +
                     red[2][mt * 3 + 2][rr][j] + red[3][mt * 3 + 2][rr][j] + bhhp_s[32 + j];
          float rg = sigm(giP[b][j] + gr);
          float zg = sigm(giP[b][16 + j] + gz);
          float ng = tanh_f(giP[b][32 + j] + rg * gn);
          float h = hpm[b][j];
          float hn2 = (t < len_s[b]) ? ((1.f - zg) * ng + zg * h) : h;
          hpm[b][j] = hn2;
          store_pair(hpwH, hpwL, (long)(r0 + b) * 512 + hc0 + j, hn2);
        }
        grp_barrier(cnt, 32u * (++bar));
      }

      if (t + 1 < S_) build_gi(t + 1, hpwH, hpwL);
    }
  }

  // fp32 finals for the head
#pragma unroll
  for (int q = 0; q < 2; ++q) {
    int o = tid * 2 + q;
    int b = o >> 4, j = o & 15;
    hw_f[(long)(r0 + b) * 512 + hc0 + j] = hwm[b][j];
    hp_f[(long)(r0 + b) * 512 + hc0 + j] = hpm[b][j];
  }
}

// fused = tanh([hw,hp] @ fus_w.T + fus_b); h = relu(fused @ h1_w.T + h1_b);
// out = h @ h2_w.T + h2_b.   One block per batch row, fp32.
__global__ __launch_bounds__(256) void head_k(
    const float* __restrict__ hwf, const float* __restrict__ hpf,
    const float* __restrict__ fw, const float* __restrict__ fb,
    const float* __restrict__ w1, const float* __restrict__ b1,
    const float* __restrict__ w2, const float* __restrict__ b2,
    float* __restrict__ out)
{
  int b = blockIdx.x;
  int tid = threadIdx.x;
  __shared__ __align__(16) float xin[1024];
  __shared__ __align__(16) float fused[512];
  __shared__ __align__(16) float hh[512];
  for (int i = tid; i < 512; i += 256) {
    xin[i] = hwf[b * 512 + i];
    xin[512 + i] = hpf[b * 512 + i];
  }
  __syncthreads();
  for (int o = tid; o < 512; o += 256) {
    const float4* wr = reinterpret_cast<const float4*>(fw + o * 1024);
    const float4* xr = reinterpret_cast<const float4*>(xin);
    float acc = fb[o];
    for (int k = 0; k < 256; ++k) {
      float4 wv = wr[k], xv = xr[k];
      acc += wv.x * xv.x + wv.y * xv.y + wv.z * xv.z + wv.w * xv.w;
    }
    fused[o] = tanhf(acc);
  }
  __syncthreads();
  for (int o = tid; o < 512; o += 256) {
    const float4* wr = reinterpret_cast<const float4*>(w1 + o * 512);
    const float4* xr = reinterpret_cast<const float4*>(fused);
    float acc = b1[o];
    for (int k = 0; k < 128; ++k) {
      float4 wv = wr[k], xv = xr[k];
      acc += wv.x * xv.x + wv.y * xv.y + wv.z * xv.z + wv.w * xv.w;
    }
    hh[o] = fmaxf(acc, 0.f);
  }
  __syncthreads();
  if (tid < 10) {
    const float4* wr = reinterpret_cast<const float4*>(w2 + tid * 512);
    const float4* xr = reinterpret_cast<const float4*>(hh);
    float acc = b2[tid];
    for (int k = 0; k < 128; ++k) {
      float4 wv = wr[k], xv = xr[k];
      acc += wv.x * xv.x + wv.y * xv.y + wv.z * xv.z + wv.w * xv.w;
    }
    out[b * 10 + tid] = acc;
  }
}

extern "C" void kernel_launch(void* const* d_in, const int* in_sizes, int n_in,
                              void* d_out, int out_size, void* d_ws, size_t ws_size,
                              hipStream_t stream) {
  const int*   ids    = (const int*)d_in[0];
  const int*   lens   = (const int*)d_in[1];
  const float* emb    = (const float*)d_in[2];
  const float* w_ih_w = (const float*)d_in[3];
  const float* w_hh_w = (const float*)d_in[4];
  const float* b_ih_w = (const float*)d_in[5];
  const float* b_hh_w = (const float*)d_in[6];
  const float* pin_w  = (const float*)d_in[7];
  const float* pin_b  = (const float*)d_in[8];
  const float* w_ih_p = (const float*)d_in[9];
  const float* w_hh_p = (const float*)d_in[10];
  const float* b_ih_p = (const float*)d_in[11];
  const float* b_hh_p = (const float*)d_in[12];
  const float* fus_w  = (const float*)d_in[13];
  const float* fus_b  = (const float*)d_in[14];
  const float* h1_w   = (const float*)d_in[15];
  const float* h1_b   = (const float*)d_in[16];
  const float* h2_w   = (const float*)d_in[17];
  const float* h2_b   = (const float*)d_in[18];
  float* out = (float*)d_out;

  char* ws = (char*)d_ws;
  size_t off = 0;
  auto alloc = [&](size_t bytes) -> void* {
    void* p = ws + off;
    off += (bytes + 255) & ~(size_t)255;
    return p;
  };
  unsigned*        counters = (unsigned*)alloc(8 * 64 * sizeof(unsigned));
  __hip_bfloat16*  hwHi = (__hip_bfloat16*)alloc(2 * STATE_STRIDE * 2);
  __hip_bfloat16*  hwLo = (__hip_bfloat16*)alloc(2 * STATE_STRIDE * 2);
  __hip_bfloat16*  hpHi = (__hip_bfloat16*)alloc(2 * STATE_STRIDE * 2);
  __hip_bfloat16*  hpLo = (__hip_bfloat16*)alloc(2 * STATE_STRIDE * 2);
  size_t zero_bytes = off;              // counters + hw/hp pairs must start at 0
  __hip_bfloat16*  pinHi = (__hip_bfloat16*)alloc(STATE_STRIDE * 2);
  __hip_bfloat16*  pinLo = (__hip_bfloat16*)alloc(STATE_STRIDE * 2);
  float*           hw_f  = (float*)alloc(STATE_STRIDE * 4);
  float*           hp_f  = (float*)alloc(STATE_STRIDE * 4);
  __hip_bfloat16*  WihHi = (__hip_bfloat16*)alloc((size_t)1536 * 768 * 2);
  __hip_bfloat16*  WihLo = (__hip_bfloat16*)alloc((size_t)1536 * 768 * 2);
  __hip_bfloat16*  WhhHi = (__hip_bfloat16*)alloc((size_t)1536 * 512 * 2);
  __hip_bfloat16*  WhhLo = (__hip_bfloat16*)alloc((size_t)1536 * 512 * 2);
  __hip_bfloat16*  PinHi = (__hip_bfloat16*)alloc((size_t)512 * 512 * 2);
  __hip_bfloat16*  PinLo = (__hip_bfloat16*)alloc((size_t)512 * 512 * 2);
  __hip_bfloat16*  WipHi = (__hip_bfloat16*)alloc((size_t)1536 * 512 * 2);
  __hip_bfloat16*  WipLo = (__hip_bfloat16*)alloc((size_t)1536 * 512 * 2);
  __hip_bfloat16*  WhpHi = (__hip_bfloat16*)alloc((size_t)1536 * 512 * 2);
  __hip_bfloat16*  WhpLo = (__hip_bfloat16*)alloc((size_t)1536 * 512 * 2);

  hipMemsetAsync(d_ws, 0, zero_bytes, stream);
  split_hilo<<<1024, 256, 0, stream>>>(w_ih_w, WihHi, WihLo, 1536 * 768);
  split_hilo<<<1024, 256, 0, stream>>>(w_hh_w, WhhHi, WhhLo, 1536 * 512);
  split_hilo<<<512, 256, 0, stream>>>(pin_w, PinHi, PinLo, 512 * 512);
  split_hilo<<<1024, 256, 0, stream>>>(w_ih_p, WipHi, WipLo, 1536 * 512);
  split_hilo<<<1024, 256, 0, stream>>>(w_hh_p, WhpHi, WhpLo, 1536 * 512);

  // Plain launch — all 256 blocks co-resident at 1 block/CU (256 CUs), so the
  // device-scope atomic barrier is safe without the cooperative API.
  hgru_main<<<dim3(256), dim3(256), 0, stream>>>(
      ids, lens, emb, b_ih_w, b_hh_w, pin_b, b_ih_p, b_hh_p,
      WihHi, WihLo, WhhHi, WhhLo, PinHi, PinLo, WipHi, WipLo, WhpHi, WhpLo,
      hwHi, hwLo, hpHi, hpLo, pinHi, pinLo, hw_f, hp_f, counters);

  head_k<<<256, 256, 0, stream>>>(hw_f, hp_f, fus_w, fus_b, h1_w, h1_b, h2_w, h2_b, out);
}

// Round 7
// 15570.378 us; speedup vs baseline: 2.5067x; 2.5067x over previous
//
#include <hip/hip_runtime.h>
#include <hip/hip_bf16.h>

// ---------------------------------------------------------------------------
// HierarchicalGRU on MI355X — compensated double-bf16 MFMA, regular launch.
// 8 groups (g=blockIdx&7) x 32 CUs; group owns 32 batch rows; CU m owns
// hidden cols [m*16, m*16+16). Every GEMM operand is a (hi,lo) bf16 pair;
// each logical GEMM = 3 MFMA products, fp32 accumulation, fp32 LDS masters.
// R7 = R6 resubmitted (GPU acquisition timed out; kernel never ran).
// Barrier: one __threadfence (release) -> RELAXED add -> RELAXED polling
// (no per-poll cache invalidate) -> one __threadfence (acquire), thread 0
// only. R4's per-poll device-scope ACQUIRE invalidated the XCD L2 each poll
// -> 3.3GB FETCH, 39ms, 99% idle. red[][] padded [16][17] for LDS conflicts.
// ---------------------------------------------------------------------------

#define B_   256
#define S_   512
#define E_   256
#define HW_  512
#define STATE_STRIDE (B_ * HW_)

typedef __attribute__((ext_vector_type(8))) short bf16x8;
typedef __attribute__((ext_vector_type(4))) float f32x4;

__device__ __forceinline__ float sigm(float x) { return 1.f / (1.f + __expf(-x)); }
__device__ __forceinline__ float tanh_f(float x) { float e = __expf(2.f * x); return (e - 1.f) / (e + 1.f); }

__device__ __forceinline__ f32x4 mfma16(bf16x8 a, bf16x8 b, f32x4 c) {
  return __builtin_amdgcn_mfma_f32_16x16x32_bf16(a, b, c, 0, 0, 0);
}
#define MFMA3(ACC, AH, AL, BH, BL)  \
  ACC = mfma16(AH, BH, ACC);        \
  ACC = mfma16(AH, BL, ACC);        \
  ACC = mfma16(AL, BH, ACC);

__device__ __forceinline__ void store_pair(__hip_bfloat16* hi, __hip_bfloat16* lo,
                                           long idx, float v) {
  __hip_bfloat16 h = __float2bfloat16(v);
  hi[idx] = h;
  lo[idx] = __float2bfloat16(v - __bfloat162float(h));
}

// Intra-group barrier (32 blocks). One release fence -> relaxed add ->
// RELAXED polling (no per-poll cache invalidate) -> one acquire fence.
// __threadfence() is a full agent-scope fence, so it serves both roles.
__device__ __forceinline__ void grp_barrier(unsigned* cnt, unsigned target) {
  __syncthreads();
  if (threadIdx.x == 0) {
    __threadfence();   // release: make this block's writes visible agent-wide
    __hip_atomic_fetch_add(cnt, 1u, __ATOMIC_RELAXED, __HIP_MEMORY_SCOPE_AGENT);
    while (__hip_atomic_load(cnt, __ATOMIC_RELAXED, __HIP_MEMORY_SCOPE_AGENT) < target)
      __builtin_amdgcn_s_sleep(4);
    __threadfence();   // acquire: discard stale cached lines before reading
  }
  __syncthreads();
}

__global__ void split_hilo(const float* __restrict__ s,
                           __hip_bfloat16* __restrict__ hi,
                           __hip_bfloat16* __restrict__ lo, int n) {
  int i = blockIdx.x * blockDim.x + threadIdx.x;
  int st = gridDim.x * blockDim.x;
  for (; i < n; i += st) {
    float v = s[i];
    __hip_bfloat16 h = __float2bfloat16(v);
    hi[i] = h;
    lo[i] = __float2bfloat16(v - __bfloat162float(h));
  }
}

__global__ __launch_bounds__(256, 1) void hgru_main(
    const int* __restrict__ ids, const int* __restrict__ lens,
    const float* __restrict__ emb,
    const float* __restrict__ b_ih_w, const float* __restrict__ b_hh_w,
    const float* __restrict__ pin_b,
    const float* __restrict__ b_ih_p, const float* __restrict__ b_hh_p,
    const __hip_bfloat16* __restrict__ WihHi, const __hip_bfloat16* __restrict__ WihLo,
    const __hip_bfloat16* __restrict__ WhhHi, const __hip_bfloat16* __restrict__ WhhLo,
    const __hip_bfloat16* __restrict__ PinHi, const __hip_bfloat16* __restrict__ PinLo,
    const __hip_bfloat16* __restrict__ WipHi, const __hip_bfloat16* __restrict__ WipLo,
    const __hip_bfloat16* __restrict__ WhpHi, const __hip_bfloat16* __restrict__ WhpLo,
    __hip_bfloat16* hwHi, __hip_bfloat16* hwLo,     // 2 x [256][512] ping-pong each
    __hip_bfloat16* hpHi, __hip_bfloat16* hpLo,     // 2 x [256][512] ping-pong each
    __hip_bfloat16* pinHi, __hip_bfloat16* pinLo,   // [256][512]
    float* hw_f, float* hp_f,
    unsigned* counters)
{
  const int tid = threadIdx.x;
  const int g = blockIdx.x & 7;
  const int m = blockIdx.x >> 3;
  const int w = tid >> 6;
  const int l = tid & 63;
  const int lrow = l & 15;
  const int lk8 = (l >> 4) * 8;
  const int r0 = g * 32;
  const int hc0 = m * 16;
  unsigned* cnt = counters + g * 64;
  unsigned bar = 0;

  __shared__ float red[4][6][16][17];    // padded: kills 4-way write conflicts
  __shared__ float gib[4][32][48];
  __shared__ float giP[32][48];
  __shared__ float hwm[32][16];
  __shared__ float hpm[32][16];
  __shared__ float bhh_s[48], bihw_s[48], bihp_s[48], bhhp_s[48], pinb_s[16];
  __shared__ int len_s[32];
  __shared__ int ids_s[32][4];

  if (tid < 48) {
    int gcol = (tid >> 4) * 512 + hc0 + (tid & 15);
    bhh_s[tid]  = b_hh_w[gcol];
    bihw_s[tid] = b_ih_w[gcol];
    bihp_s[tid] = b_ih_p[gcol];
    bhhp_s[tid] = b_hh_p[gcol];
  }
  if (tid < 16) pinb_s[tid] = pin_b[hc0 + tid];
  if (tid < 32) len_s[tid] = lens[r0 + tid];
  {
    int o = tid * 2;
    hwm[o >> 4][o & 15] = 0.f; hpm[o >> 4][o & 15] = 0.f;
    o++;
    hwm[o >> 4][o & 15] = 0.f; hpm[o >> 4][o & 15] = 0.f;
  }
  __syncthreads();

  // ---- VGPR-resident hi/lo weight fragments (per-wave K-slice of 128) ----
  bf16x8 whh_h[3][4], whh_l[3][4], wip_h[3][4], wip_l[3][4], whp_h[3][4], whp_l[3][4];
#pragma unroll
  for (int nt = 0; nt < 3; ++nt)
#pragma unroll
    for (int kt = 0; kt < 4; ++kt) {
      long o = (long)(nt * 512 + hc0 + lrow) * 512 + w * 128 + kt * 32 + lk8;
      whh_h[nt][kt] = *(const bf16x8*)(WhhHi + o);
      whh_l[nt][kt] = *(const bf16x8*)(WhhLo + o);
      wip_h[nt][kt] = *(const bf16x8*)(WipHi + o);
      wip_l[nt][kt] = *(const bf16x8*)(WipLo + o);
      whp_h[nt][kt] = *(const bf16x8*)(WhpHi + o);
      whp_l[nt][kt] = *(const bf16x8*)(WhpLo + o);
    }

  // ---- helper: rebuild gi_base for chunk [tbase, tbase+4) from hp pair ----
  auto build_gi = [&](int tbase, const __hip_bfloat16* hpH, const __hip_bfloat16* hpL) {
    if (tid < 128) {
      int r = tid >> 2, tp = tid & 3;
      ids_s[r][tp] = ids[(r0 + r) * S_ + tbase + tp];
    }
    bf16x8 ah[2][4], al[2][4];
#pragma unroll
    for (int mt = 0; mt < 2; ++mt)
#pragma unroll
      for (int kt = 0; kt < 4; ++kt) {
        long o = (long)(r0 + mt * 16 + lrow) * 512 + w * 128 + kt * 32 + lk8;
        ah[mt][kt] = *(const bf16x8*)(hpH + o);
        al[mt][kt] = *(const bf16x8*)(hpL + o);
      }
    f32x4 acc[6];
#pragma unroll
    for (int i = 0; i < 6; ++i) acc[i] = 0.f;
#pragma unroll
    for (int nt = 0; nt < 3; ++nt)
#pragma unroll
      for (int kt = 0; kt < 4; ++kt) {
        long o = (long)(nt * 512 + hc0 + lrow) * 768 + 256 + w * 128 + kt * 32 + lk8;
        bf16x8 bh = *(const bf16x8*)(WihHi + o);
        bf16x8 bl = *(const bf16x8*)(WihLo + o);
        MFMA3(acc[0 * 3 + nt], ah[0][kt], al[0][kt], bh, bl);
        MFMA3(acc[1 * 3 + nt], ah[1][kt], al[1][kt], bh, bl);
      }
#pragma unroll
    for (int tile = 0; tile < 6; ++tile)
#pragma unroll
      for (int r = 0; r < 4; ++r)
        red[w][tile][(l >> 4) * 4 + r][l & 15] = acc[tile][r];
    __syncthreads();
#pragma unroll
    for (int q = 0; q < 6; ++q) {
      int o = q * 256 + tid;
      int b = o / 48, c = o - b * 48;
      int tile = (b >> 4) * 3 + (c >> 4);
      float v = red[0][tile][b & 15][c & 15] + red[1][tile][b & 15][c & 15] +
                red[2][tile][b & 15][c & 15] + red[3][tile][b & 15][c & 15];
      v += bihw_s[c];
      gib[0][b][c] = v; gib[1][b][c] = v; gib[2][b][c] = v; gib[3][b][c] = v;
    }
    __syncthreads();
    bf16x8 bxh[3][2], bxl[3][2];
#pragma unroll
    for (int nt = 0; nt < 3; ++nt)
#pragma unroll
      for (int kt = 0; kt < 2; ++kt) {
        long o = (long)(nt * 512 + hc0 + lrow) * 768 + w * 64 + kt * 32 + lk8;
        bxh[nt][kt] = *(const bf16x8*)(WihHi + o);
        bxl[nt][kt] = *(const bf16x8*)(WihLo + o);
      }
    for (int tp = 0; tp < 4; ++tp) {
      bf16x8 axh[2][2], axl[2][2];
#pragma unroll
      for (int mt = 0; mt < 2; ++mt) {
        int id = ids_s[mt * 16 + lrow][tp];
        const float* ep = emb + (long)id * E_ + w * 64 + lk8;
#pragma unroll
        for (int kt = 0; kt < 2; ++kt) {
          float4 e0 = *reinterpret_cast<const float4*>(ep + kt * 32);
          float4 e1 = *reinterpret_cast<const float4*>(ep + kt * 32 + 4);
          float ef[8] = {e0.x, e0.y, e0.z, e0.w, e1.x, e1.y, e1.z, e1.w};
          bf16x8 vh, vl;
#pragma unroll
          for (int j = 0; j < 8; ++j) {
            __hip_bfloat16 hb = __float2bfloat16(ef[j]);
            __hip_bfloat16 lb = __float2bfloat16(ef[j] - __bfloat162float(hb));
            vh[j] = *reinterpret_cast<short*>(&hb);
            vl[j] = *reinterpret_cast<short*>(&lb);
          }
          axh[mt][kt] = vh; axl[mt][kt] = vl;
        }
      }
      f32x4 a2[6];
#pragma unroll
      for (int i = 0; i < 6; ++i) a2[i] = 0.f;
#pragma unroll
      for (int nt = 0; nt < 3; ++nt)
#pragma unroll
        for (int kt = 0; kt < 2; ++kt) {
          MFMA3(a2[0 * 3 + nt], axh[0][kt], axl[0][kt], bxh[nt][kt], bxl[nt][kt]);
          MFMA3(a2[1 * 3 + nt], axh[1][kt], axl[1][kt], bxh[nt][kt], bxl[nt][kt]);
        }
#pragma unroll
      for (int tile = 0; tile < 6; ++tile)
#pragma unroll
        for (int r = 0; r < 4; ++r)
          red[w][tile][(l >> 4) * 4 + r][l & 15] = a2[tile][r];
      __syncthreads();
#pragma unroll
      for (int q = 0; q < 6; ++q) {
        int o = q * 256 + tid;
        int b = o / 48, c = o - b * 48;
        int tile = (b >> 4) * 3 + (c >> 4);
        gib[tp][b][c] += red[0][tile][b & 15][c & 15] + red[1][tile][b & 15][c & 15] +
                         red[2][tile][b & 15][c & 15] + red[3][tile][b & 15][c & 15];
      }
      __syncthreads();
    }
  };

  build_gi(0, hpHi, hpLo);   // hp == 0 initially (buffers zeroed by memset)

#pragma unroll 1
  for (int t = 0; t < S_; ++t) {
    // ---------------- worker step ----------------
    {
      const __hip_bfloat16* hrH = hwHi + (t & 1) * STATE_STRIDE;
      const __hip_bfloat16* hrL = hwLo + (t & 1) * STATE_STRIDE;
      __hip_bfloat16* hwpH = hwHi + ((t & 1) ^ 1) * STATE_STRIDE;
      __hip_bfloat16* hwpL = hwLo + ((t & 1) ^ 1) * STATE_STRIDE;
      bf16x8 ah[2][4], al[2][4];
#pragma unroll
      for (int mt = 0; mt < 2; ++mt)
#pragma unroll
        for (int kt = 0; kt < 4; ++kt) {
          long o = (long)(r0 + mt * 16 + lrow) * 512 + w * 128 + kt * 32 + lk8;
          ah[mt][kt] = *(const bf16x8*)(hrH + o);
          al[mt][kt] = *(const bf16x8*)(hrL + o);
        }
      f32x4 acc[6];
#pragma unroll
      for (int i = 0; i < 6; ++i) acc[i] = 0.f;
#pragma unroll
      for (int kt = 0; kt < 4; ++kt)
#pragma unroll
        for (int nt = 0; nt < 3; ++nt) {
          MFMA3(acc[0 * 3 + nt], ah[0][kt], al[0][kt], whh_h[nt][kt], whh_l[nt][kt]);
          MFMA3(acc[1 * 3 + nt], ah[1][kt], al[1][kt], whh_h[nt][kt], whh_l[nt][kt]);
        }
#pragma unroll
      for (int tile = 0; tile < 6; ++tile)
#pragma unroll
        for (int r = 0; r < 4; ++r)
          red[w][tile][(l >> 4) * 4 + r][l & 15] = acc[tile][r];
      __syncthreads();
      int tc = t & 3;
#pragma unroll
      for (int q = 0; q < 2; ++q) {
        int o = tid * 2 + q;
        int b = o >> 4, j = o & 15, mt = b >> 4, rr = b & 15;
        float gr = red[0][mt * 3 + 0][rr][j] + red[1][mt * 3 + 0][rr][j] +
                   red[2][mt * 3 + 0][rr][j] + red[3][mt * 3 + 0][rr][j] + bhh_s[j];
        float gz = red[0][mt * 3 + 1][rr][j] + red[1][mt * 3 + 1][rr][j] +
                   red[2][mt * 3 + 1][rr][j] + red[3][mt * 3 + 1][rr][j] + bhh_s[16 + j];
        float gn = red[0][mt * 3 + 2][rr][j] + red[1][mt * 3 + 2][rr][j] +
                   red[2][mt * 3 + 2][rr][j] + red[3][mt * 3 + 2][rr][j] + bhh_s[32 + j];
        float rg = sigm(gib[tc][b][j] + gr);
        float zg = sigm(gib[tc][b][16 + j] + gz);
        float ng = tanh_f(gib[tc][b][32 + j] + rg * gn);
        float h = hwm[b][j];
        float hn2 = (t < len_s[b]) ? ((1.f - zg) * ng + zg * h) : h;
        hwm[b][j] = hn2;
        store_pair(hwpH, hwpL, (long)(r0 + b) * 512 + hc0 + j, hn2);
      }
      grp_barrier(cnt, 32u * (++bar));
    }

    // ---------------- planner (every 4th step) ----------------
    if (((t + 1) & 3) == 0) {
      const __hip_bfloat16* hrH = hwHi + ((t & 1) ^ 1) * STATE_STRIDE;  // post-update hw
      const __hip_bfloat16* hrL = hwLo + ((t & 1) ^ 1) * STATE_STRIDE;
      int c = t >> 2;
      const __hip_bfloat16* hprH = hpHi + (c & 1) * STATE_STRIDE;
      const __hip_bfloat16* hprL = hpLo + (c & 1) * STATE_STRIDE;
      __hip_bfloat16* hpwH = hpHi + ((c & 1) ^ 1) * STATE_STRIDE;
      __hip_bfloat16* hpwL = hpLo + ((c & 1) ^ 1) * STATE_STRIDE;

      // pin = hw @ pin_w.T + pin_b (own 16 cols); Pin streamed from L2
      {
        bf16x8 ah[2][4], al[2][4];
#pragma unroll
        for (int mt = 0; mt < 2; ++mt)
#pragma unroll
          for (int kt = 0; kt < 4; ++kt) {
            long o = (long)(r0 + mt * 16 + lrow) * 512 + w * 128 + kt * 32 + lk8;
            ah[mt][kt] = *(const bf16x8*)(hrH + o);
            al[mt][kt] = *(const bf16x8*)(hrL + o);
          }
        f32x4 pa[2];
        pa[0] = 0.f; pa[1] = 0.f;
#pragma unroll
        for (int kt = 0; kt < 4; ++kt) {
          long o = (long)(hc0 + lrow) * 512 + w * 128 + kt * 32 + lk8;
          bf16x8 bnh = *(const bf16x8*)(PinHi + o);
          bf16x8 bnl = *(const bf16x8*)(PinLo + o);
          MFMA3(pa[0], ah[0][kt], al[0][kt], bnh, bnl);
          MFMA3(pa[1], ah[1][kt], al[1][kt], bnh, bnl);
        }
#pragma unroll
        for (int mt = 0; mt < 2; ++mt)
#pragma unroll
          for (int r = 0; r < 4; ++r)
            red[w][mt][(l >> 4) * 4 + r][l & 15] = pa[mt][r];
        __syncthreads();
#pragma unroll
        for (int q = 0; q < 2; ++q) {
          int o = tid * 2 + q;
          int b = o >> 4, j = o & 15;
          float v = red[0][b >> 4][b & 15][j] + red[1][b >> 4][b & 15][j] +
                    red[2][b >> 4][b & 15][j] + red[3][b >> 4][b & 15][j] + pinb_s[j];
          store_pair(pinHi, pinLo, (long)(r0 + b) * 512 + hc0 + j, v);
        }
        grp_barrier(cnt, 32u * (++bar));
      }

      // planner GRU gates
      {
        bf16x8 ah[2][4], al[2][4];
#pragma unroll
        for (int mt = 0; mt < 2; ++mt)
#pragma unroll
          for (int kt = 0; kt < 4; ++kt) {
            long o = (long)(r0 + mt * 16 + lrow) * 512 + w * 128 + kt * 32 + lk8;
            ah[mt][kt] = *(const bf16x8*)(pinHi + o);
            al[mt][kt] = *(const bf16x8*)(pinLo + o);
          }
        f32x4 acc[6];
#pragma unroll
        for (int i = 0; i < 6; ++i) acc[i] = 0.f;
#pragma unroll
        for (int nt = 0; nt < 3; ++nt)
#pragma unroll
          for (int kt = 0; kt < 4; ++kt) {
            MFMA3(acc[0 * 3 + nt], ah[0][kt], al[0][kt], wip_h[nt][kt], wip_l[nt][kt]);
            MFMA3(acc[1 * 3 + nt], ah[1][kt], al[1][kt], wip_h[nt][kt], wip_l[nt][kt]);
          }
#pragma unroll
        for (int tile = 0; tile < 6; ++tile)
#pragma unroll
          for (int r = 0; r < 4; ++r)
            red[w][tile][(l >> 4) * 4 + r][l & 15] = acc[tile][r];
        __syncthreads();
#pragma unroll
        for (int q = 0; q < 6; ++q) {
          int o = q * 256 + tid;
          int b = o / 48, cc = o - b * 48;
          int tile = (b >> 4) * 3 + (cc >> 4);
          giP[b][cc] = red[0][tile][b & 15][cc & 15] + red[1][tile][b & 15][cc & 15] +
                       red[2][tile][b & 15][cc & 15] + red[3][tile][b & 15][cc & 15] +
                       bihp_s[cc];
        }
        __syncthreads();
#pragma unroll
        for (int mt = 0; mt < 2; ++mt)
#pragma unroll
          for (int kt = 0; kt < 4; ++kt) {
            long o = (long)(r0 + mt * 16 + lrow) * 512 + w * 128 + kt * 32 + lk8;
            ah[mt][kt] = *(const bf16x8*)(hprH + o);
            al[mt][kt] = *(const bf16x8*)(hprL + o);
          }
#pragma unroll
        for (int i = 0; i < 6; ++i) acc[i] = 0.f;
#pragma unroll
        for (int nt = 0; nt < 3; ++nt)
#pragma unroll
          for (int kt = 0; kt < 4; ++kt) {
            MFMA3(acc[0 * 3 + nt], ah[0][kt], al[0][kt], whp_h[nt][kt], whp_l[nt][kt]);
            MFMA3(acc[1 * 3 + nt], ah[1][kt], al[1][kt], whp_h[nt][kt], whp_l[nt][kt]);
          }
#pragma unroll
        for (int tile = 0; tile < 6; ++tile)
#pragma unroll
          for (int r = 0; r < 4; ++r)
            red[w][tile][(l >> 4) * 4 + r][l & 15] = acc[tile][r];
        __syncthreads();
#pragma unroll
        for (int q = 0; q < 2; ++q) {
          int o = tid * 2 + q;
          int b = o >> 4, j = o & 15, mt = b >> 4, rr = b & 15;
          float gr = red[0][mt * 3 + 0][rr][j] + red[1][mt * 3 + 0][rr][j] +
                     red[2][mt * 3 + 0][rr][j] + red[3][mt * 3 + 0][rr][j] + bhhp_s[j];
          float gz = red[0][mt * 3 + 1][rr][j] + red[1][mt * 3 + 1][rr][j] +
                     red[2][mt * 3 + 1][rr][j] + red[3][mt * 3 + 1][rr][j] + bhhp_s[16 + j];
          float gn = red[0][mt * 3 + 2][rr][j] + red[1][mt * 3 + 2][rr][j] +
                     red[2][mt * 3 + 2][rr][j] + red[3][mt * 3 + 2][rr][j] + bhhp_s[32 + j];
          float rg = sigm(giP[b][j] + gr);
          float zg = sigm(giP[b][16 + j] + gz);
          float ng = tanh_f(giP[b][32 + j] + rg * gn);
          float h = hpm[b][j];
          float hn2 = (t < len_s[b]) ? ((1.f - zg) * ng + zg * h) : h;
          hpm[b][j] = hn2;
          store_pair(hpwH, hpwL, (long)(r0 + b) * 512 + hc0 + j, hn2);
        }
        grp_barrier(cnt, 32u * (++bar));
      }

      if (t + 1 < S_) build_gi(t + 1, hpwH, hpwL);
    }
  }

  // fp32 finals for the head
#pragma unroll
  for (int q = 0; q < 2; ++q) {
    int o = tid * 2 + q;
    int b = o >> 4, j = o & 15;
    hw_f[(long)(r0 + b) * 512 + hc0 + j] = hwm[b][j];
    hp_f[(long)(r0 + b) * 512 + hc0 + j] = hpm[b][j];
  }
}

// fused = tanh([hw,hp] @ fus_w.T + fus_b); h = relu(fused @ h1_w.T + h1_b);
// out = h @ h2_w.T + h2_b.   One block per batch row, fp32.
__global__ __launch_bounds__(256) void head_k(
    const float* __restrict__ hwf, const float* __restrict__ hpf,
    const float* __restrict__ fw, const float* __restrict__ fb,
    const float* __restrict__ w1, const float* __restrict__ b1,
    const float* __restrict__ w2, const float* __restrict__ b2,
    float* __restrict__ out)
{
  int b = blockIdx.x;
  int tid = threadIdx.x;
  __shared__ __align__(16) float xin[1024];
  __shared__ __align__(16) float fused[512];
  __shared__ __align__(16) float hh[512];
  for (int i = tid; i < 512; i += 256) {
    xin[i] = hwf[b * 512 + i];
    xin[512 + i] = hpf[b * 512 + i];
  }
  __syncthreads();
  for (int o = tid; o < 512; o += 256) {
    const float4* wr = reinterpret_cast<const float4*>(fw + o * 1024);
    const float4* xr = reinterpret_cast<const float4*>(xin);
    float acc = fb[o];
    for (int k = 0; k < 256; ++k) {
      float4 wv = wr[k], xv = xr[k];
      acc += wv.x * xv.x + wv.y * xv.y + wv.z * xv.z + wv.w * xv.w;
    }
    fused[o] = tanhf(acc);
  }
  __syncthreads();
  for (int o = tid; o < 512; o += 256) {
    const float4* wr = reinterpret_cast<const float4*>(w1 + o * 512);
    const float4* xr = reinterpret_cast<const float4*>(fused);
    float acc = b1[o];
    for (int k = 0; k < 128; ++k) {
      float4 wv = wr[k], xv = xr[k];
      acc += wv.x * xv.x + wv.y * xv.y + wv.z * xv.z + wv.w * xv.w;
    }
    hh[o] = fmaxf(acc, 0.f);
  }
  __syncthreads();
  if (tid < 10) {
    const float4* wr = reinterpret_cast<const float4*>(w2 + tid * 512);
    const float4* xr = reinterpret_cast<const float4*>(hh);
    float acc = b2[tid];
    for (int k = 0; k < 128; ++k) {
      float4 wv = wr[k], xv = xr[k];
      acc += wv.x * xv.x + wv.y * xv.y + wv.z * xv.z + wv.w * xv.w;
    }
    out[b * 10 + tid] = acc;
  }
}

extern "C" void kernel_launch(void* const* d_in, const int* in_sizes, int n_in,
                              void* d_out, int out_size, void* d_ws, size_t ws_size,
                              hipStream_t stream) {
  const int*   ids    = (const int*)d_in[0];
  const int*   lens   = (const int*)d_in[1];
  const float* emb    = (const float*)d_in[2];
  const float* w_ih_w = (const float*)d_in[3];
  const float* w_hh_w = (const float*)d_in[4];
  const float* b_ih_w = (const float*)d_in[5];
  const float* b_hh_w = (const float*)d_in[6];
  const float* pin_w  = (const float*)d_in[7];
  const float* pin_b  = (const float*)d_in[8];
  const float* w_ih_p = (const float*)d_in[9];
  const float* w_hh_p = (const float*)d_in[10];
  const float* b_ih_p = (const float*)d_in[11];
  const float* b_hh_p = (const float*)d_in[12];
  const float* fus_w  = (const float*)d_in[13];
  const float* fus_b  = (const float*)d_in[14];
  const float* h1_w   = (const float*)d_in[15];
  const float* h1_b   = (const float*)d_in[16];
  const float* h2_w   = (const float*)d_in[17];
  const float* h2_b   = (const float*)d_in[18];
  float* out = (float*)d_out;

  char* ws = (char*)d_ws;
  size_t off = 0;
  auto alloc = [&](size_t bytes) -> void* {
    void* p = ws + off;
    off += (bytes + 255) & ~(size_t)255;
    return p;
  };
  unsigned*        counters = (unsigned*)alloc(8 * 64 * sizeof(unsigned));
  __hip_bfloat16*  hwHi = (__hip_bfloat16*)alloc(2 * STATE_STRIDE * 2);
  __hip_bfloat16*  hwLo = (__hip_bfloat16*)alloc(2 * STATE_STRIDE * 2);
  __hip_bfloat16*  hpHi = (__hip_bfloat16*)alloc(2 * STATE_STRIDE * 2);
  __hip_bfloat16*  hpLo = (__hip_bfloat16*)alloc(2 * STATE_STRIDE * 2);
  size_t zero_bytes = off;              // counters + hw/hp pairs must start at 0
  __hip_bfloat16*  pinHi = (__hip_bfloat16*)alloc(STATE_STRIDE * 2);
  __hip_bfloat16*  pinLo = (__hip_bfloat16*)alloc(STATE_STRIDE * 2);
  float*           hw_f  = (float*)alloc(STATE_STRIDE * 4);
  float*           hp_f  = (float*)alloc(STATE_STRIDE * 4);
  __hip_bfloat16*  WihHi = (__hip_bfloat16*)alloc((size_t)1536 * 768 * 2);
  __hip_bfloat16*  WihLo = (__hip_bfloat16*)alloc((size_t)1536 * 768 * 2);
  __hip_bfloat16*  WhhHi = (__hip_bfloat16*)alloc((size_t)1536 * 512 * 2);
  __hip_bfloat16*  WhhLo = (__hip_bfloat16*)alloc((size_t)1536 * 512 * 2);
  __hip_bfloat16*  PinHi = (__hip_bfloat16*)alloc((size_t)512 * 512 * 2);
  __hip_bfloat16*  PinLo = (__hip_bfloat16*)alloc((size_t)512 * 512 * 2);
  __hip_bfloat16*  WipHi = (__hip_bfloat16*)alloc((size_t)1536 * 512 * 2);
  __hip_bfloat16*  WipLo = (__hip_bfloat16*)alloc((size_t)1536 * 512 * 2);
  __hip_bfloat16*  WhpHi = (__hip_bfloat16*)alloc((size_t)1536 * 512 * 2);
  __hip_bfloat16*  WhpLo = (__hip_bfloat16*)alloc((size_t)1536 * 512 * 2);

  (void)hipMemsetAsync(d_ws, 0, zero_bytes, stream);
  split_hilo<<<1024, 256, 0, stream>>>(w_ih_w, WihHi, WihLo, 1536 * 768);
  split_hilo<<<1024, 256, 0, stream>>>(w_hh_w, WhhHi, WhhLo, 1536 * 512);
  split_hilo<<<512, 256, 0, stream>>>(pin_w, PinHi, PinLo, 512 * 512);
  split_hilo<<<1024, 256, 0, stream>>>(w_ih_p, WipHi, WipLo, 1536 * 512);
  split_hilo<<<1024, 256, 0, stream>>>(w_hh_p, WhpHi, WhpLo, 1536 * 512);

  // Plain launch — all 256 blocks co-resident at 1 block/CU (256 CUs), so the
  // device-scope atomic barrier is safe without the cooperative API.
  hgru_main<<<dim3(256), dim3(256), 0, stream>>>(
      ids, lens, emb, b_ih_w, b_hh_w, pin_b, b_ih_p, b_hh_p,
      WihHi, WihLo, WhhHi, WhhLo, PinHi, PinLo, WipHi, WipLo, WhpHi, WhpLo,
      hwHi, hwLo, hpHi, hpLo, pinHi, pinLo, hw_f, hp_f, counters);

  head_k<<<256, 256, 0, stream>>>(hw_f, hp_f, fus_w, fus_b, h1_w, h1_b, h2_w, h2_b, out);
}

// Round 8
// 7368.344 us; speedup vs baseline: 5.2971x; 2.1131x over previous
//
#include <hip/hip_runtime.h>
#include <hip/hip_bf16.h>

// ---------------------------------------------------------------------------
// HierarchicalGRU on MI355X — compensated double-bf16 MFMA, regular launch.
// 8 groups (g=blockIdx&7) x 32 CUs; group owns 32 batch rows; CU m owns
// hidden cols [m*16, m*16+16). Every GEMM operand is a (hi,lo) bf16 pair;
// each logical GEMM = 3 MFMA products, fp32 accumulation, fp32 LDS masters.
// R8 change (from R7 counters: FETCH still 3.4GB, dur 15.6ms, MfmaUtil 3.7%):
// __threadfence() per barrier was invalidating the XCD L2 every step, forcing
// per-chunk weight streams (Wih/Pin, ~5.7MB/group) to re-fetch continuously.
// NEW: zero fences. State exchange (hw/hp/pin pairs) uses sc0 sc1 coherent
// global ops (write-through to L3; loads bypass L1/L2) — mapping-independent
// correctness with no cache invalidation, so weights stay hot in L2.
// Barrier: per-block flag array (64B-padded); writer stores its round number
// (after __syncthreads drains vmcnt); wave-0 lanes poll all 32 flags in
// PARALLEL (removes the 32-serialized-atomic chain of the counter barrier).
// ---------------------------------------------------------------------------

#define B_   256
#define S_   512
#define E_   256
#define HW_  512
#define STATE_STRIDE (B_ * HW_)

typedef __attribute__((ext_vector_type(8))) short bf16x8;
typedef __attribute__((ext_vector_type(4))) float f32x4;

__device__ __forceinline__ float sigm(float x) { return 1.f / (1.f + __expf(-x)); }
__device__ __forceinline__ float tanh_f(float x) { float e = __expf(2.f * x); return (e - 1.f) / (e + 1.f); }

__device__ __forceinline__ f32x4 mfma16(bf16x8 a, bf16x8 b, f32x4 c) {
  return __builtin_amdgcn_mfma_f32_16x16x32_bf16(a, b, c, 0, 0, 0);
}
#define MFMA3(ACC, AH, AL, BH, BL)  \
  ACC = mfma16(AH, BH, ACC);        \
  ACC = mfma16(AH, BL, ACC);        \
  ACC = mfma16(AL, BH, ACC);

// Coherent (device-scope, fence-free) state access: sc0 sc1 bypasses L1/L2 so
// readers always see the L3/coherence-point copy; writers write through to it.
__device__ __forceinline__ void ld_pair_sc(const __hip_bfloat16* ph,
                                           const __hip_bfloat16* pl,
                                           bf16x8& oh, bf16x8& ol) {
  asm volatile("global_load_dwordx4 %0, %2, off sc0 sc1\n\t"
               "global_load_dwordx4 %1, %3, off sc0 sc1\n\t"
               "s_waitcnt vmcnt(0)"
               : "=&v"(oh), "=&v"(ol)
               : "v"(ph), "v"(pl)
               : "memory");
}
__device__ __forceinline__ void st_pair_sc(__hip_bfloat16* hi, __hip_bfloat16* lo,
                                           long idx, float v) {
  __hip_bfloat16 h = __float2bfloat16(v);
  __hip_bfloat16 l2 = __float2bfloat16(v - __bfloat162float(h));
  unsigned hv = *(unsigned short*)&h;
  unsigned lv = *(unsigned short*)&l2;
  asm volatile("global_store_short %0, %1, off sc0 sc1" :: "v"(hi + idx), "v"(hv) : "memory");
  asm volatile("global_store_short %0, %1, off sc0 sc1" :: "v"(lo + idx), "v"(lv) : "memory");
}

// Intra-group barrier via per-block flags (64B padded). No fences, no RMW.
// Writer: all waves drain their stores (explicit vmcnt + the one __syncthreads
// emits), then thread 0 publishes its round number system-coherently.
// Wave 0's 32 lanes poll the 32 flags in parallel. Monotonic rounds +
// ping-pong state buffers tolerate the permitted 1-round skew.
__device__ __forceinline__ void grp_barrier(unsigned* flagsG, int m, unsigned bar) {
  asm volatile("s_waitcnt vmcnt(0)" ::: "memory");   // per-wave drain of sc-stores
  __syncthreads();
  if (threadIdx.x == 0)
    __hip_atomic_store(flagsG + m * 16, bar, __ATOMIC_RELAXED, __HIP_MEMORY_SCOPE_SYSTEM);
  if (threadIdx.x < 32) {
    while (__hip_atomic_load(flagsG + threadIdx.x * 16, __ATOMIC_RELAXED,
                             __HIP_MEMORY_SCOPE_SYSTEM) < bar)
      __builtin_amdgcn_s_sleep(2);
  }
  __syncthreads();
}

__global__ void split_hilo(const float* __restrict__ s,
                           __hip_bfloat16* __restrict__ hi,
                           __hip_bfloat16* __restrict__ lo, int n) {
  int i = blockIdx.x * blockDim.x + threadIdx.x;
  int st = gridDim.x * blockDim.x;
  for (; i < n; i += st) {
    float v = s[i];
    __hip_bfloat16 h = __float2bfloat16(v);
    hi[i] = h;
    lo[i] = __float2bfloat16(v - __bfloat162float(h));
  }
}

__global__ __launch_bounds__(256, 1) void hgru_main(
    const int* __restrict__ ids, const int* __restrict__ lens,
    const float* __restrict__ emb,
    const float* __restrict__ b_ih_w, const float* __restrict__ b_hh_w,
    const float* __restrict__ pin_b,
    const float* __restrict__ b_ih_p, const float* __restrict__ b_hh_p,
    const __hip_bfloat16* __restrict__ WihHi, const __hip_bfloat16* __restrict__ WihLo,
    const __hip_bfloat16* __restrict__ WhhHi, const __hip_bfloat16* __restrict__ WhhLo,
    const __hip_bfloat16* __restrict__ PinHi, const __hip_bfloat16* __restrict__ PinLo,
    const __hip_bfloat16* __restrict__ WipHi, const __hip_bfloat16* __restrict__ WipLo,
    const __hip_bfloat16* __restrict__ WhpHi, const __hip_bfloat16* __restrict__ WhpLo,
    __hip_bfloat16* hwHi, __hip_bfloat16* hwLo,     // 2 x [256][512] ping-pong each
    __hip_bfloat16* hpHi, __hip_bfloat16* hpLo,     // 2 x [256][512] ping-pong each
    __hip_bfloat16* pinHi, __hip_bfloat16* pinLo,   // [256][512]
    float* hw_f, float* hp_f,
    unsigned* flags)                                 // 8 groups x 32 flags x 16 dwords
{
  const int tid = threadIdx.x;
  const int g = blockIdx.x & 7;
  const int m = blockIdx.x >> 3;
  const int w = tid >> 6;
  const int l = tid & 63;
  const int lrow = l & 15;
  const int lk8 = (l >> 4) * 8;
  const int r0 = g * 32;
  const int hc0 = m * 16;
  unsigned* flagsG = flags + g * 512;
  unsigned bar = 0;

  __shared__ float red[4][6][16][17];    // padded: kills 4-way write conflicts
  __shared__ float gib[4][32][48];
  __shared__ float giP[32][48];
  __shared__ float hwm[32][16];
  __shared__ float hpm[32][16];
  __shared__ float bhh_s[48], bihw_s[48], bihp_s[48], bhhp_s[48], pinb_s[16];
  __shared__ int len_s[32];
  __shared__ int ids_s[32][4];

  if (tid < 48) {
    int gcol = (tid >> 4) * 512 + hc0 + (tid & 15);
    bhh_s[tid]  = b_hh_w[gcol];
    bihw_s[tid] = b_ih_w[gcol];
    bihp_s[tid] = b_ih_p[gcol];
    bhhp_s[tid] = b_hh_p[gcol];
  }
  if (tid < 16) pinb_s[tid] = pin_b[hc0 + tid];
  if (tid < 32) len_s[tid] = lens[r0 + tid];
  {
    int o = tid * 2;
    hwm[o >> 4][o & 15] = 0.f; hpm[o >> 4][o & 15] = 0.f;
    o++;
    hwm[o >> 4][o & 15] = 0.f; hpm[o >> 4][o & 15] = 0.f;
  }
  __syncthreads();

  // ---- VGPR-resident hi/lo weight fragments (per-wave K-slice of 128) ----
  bf16x8 whh_h[3][4], whh_l[3][4], wip_h[3][4], wip_l[3][4], whp_h[3][4], whp_l[3][4];
#pragma unroll
  for (int nt = 0; nt < 3; ++nt)
#pragma unroll
    for (int kt = 0; kt < 4; ++kt) {
      long o = (long)(nt * 512 + hc0 + lrow) * 512 + w * 128 + kt * 32 + lk8;
      whh_h[nt][kt] = *(const bf16x8*)(WhhHi + o);
      whh_l[nt][kt] = *(const bf16x8*)(WhhLo + o);
      wip_h[nt][kt] = *(const bf16x8*)(WipHi + o);
      wip_l[nt][kt] = *(const bf16x8*)(WipLo + o);
      whp_h[nt][kt] = *(const bf16x8*)(WhpHi + o);
      whp_l[nt][kt] = *(const bf16x8*)(WhpLo + o);
    }

  // ---- helper: rebuild gi_base for chunk [tbase, tbase+4) from hp pair ----
  auto build_gi = [&](int tbase, const __hip_bfloat16* hpH, const __hip_bfloat16* hpL) {
    if (tid < 128) {
      int r = tid >> 2, tp = tid & 3;
      ids_s[r][tp] = ids[(r0 + r) * S_ + tbase + tp];
    }
    bf16x8 ah[2][4], al[2][4];
#pragma unroll
    for (int mt = 0; mt < 2; ++mt)
#pragma unroll
      for (int kt = 0; kt < 4; ++kt) {
        long o = (long)(r0 + mt * 16 + lrow) * 512 + w * 128 + kt * 32 + lk8;
        ld_pair_sc(hpH + o, hpL + o, ah[mt][kt], al[mt][kt]);
      }
    f32x4 acc[6];
#pragma unroll
    for (int i = 0; i < 6; ++i) acc[i] = 0.f;
#pragma unroll
    for (int nt = 0; nt < 3; ++nt)
#pragma unroll
      for (int kt = 0; kt < 4; ++kt) {
        long o = (long)(nt * 512 + hc0 + lrow) * 768 + 256 + w * 128 + kt * 32 + lk8;
        bf16x8 bh = *(const bf16x8*)(WihHi + o);
        bf16x8 bl = *(const bf16x8*)(WihLo + o);
        MFMA3(acc[0 * 3 + nt], ah[0][kt], al[0][kt], bh, bl);
        MFMA3(acc[1 * 3 + nt], ah[1][kt], al[1][kt], bh, bl);
      }
#pragma unroll
    for (int tile = 0; tile < 6; ++tile)
#pragma unroll
      for (int r = 0; r < 4; ++r)
        red[w][tile][(l >> 4) * 4 + r][l & 15] = acc[tile][r];
    __syncthreads();
#pragma unroll
    for (int q = 0; q < 6; ++q) {
      int o = q * 256 + tid;
      int b = o / 48, c = o - b * 48;
      int tile = (b >> 4) * 3 + (c >> 4);
      float v = red[0][tile][b & 15][c & 15] + red[1][tile][b & 15][c & 15] +
                red[2][tile][b & 15][c & 15] + red[3][tile][b & 15][c & 15];
      v += bihw_s[c];
      gib[0][b][c] = v; gib[1][b][c] = v; gib[2][b][c] = v; gib[3][b][c] = v;
    }
    __syncthreads();
    bf16x8 bxh[3][2], bxl[3][2];
#pragma unroll
    for (int nt = 0; nt < 3; ++nt)
#pragma unroll
      for (int kt = 0; kt < 2; ++kt) {
        long o = (long)(nt * 512 + hc0 + lrow) * 768 + w * 64 + kt * 32 + lk8;
        bxh[nt][kt] = *(const bf16x8*)(WihHi + o);
        bxl[nt][kt] = *(const bf16x8*)(WihLo + o);
      }
    for (int tp = 0; tp < 4; ++tp) {
      bf16x8 axh[2][2], axl[2][2];
#pragma unroll
      for (int mt = 0; mt < 2; ++mt) {
        int id = ids_s[mt * 16 + lrow][tp];
        const float* ep = emb + (long)id * E_ + w * 64 + lk8;
#pragma unroll
        for (int kt = 0; kt < 2; ++kt) {
          float4 e0 = *reinterpret_cast<const float4*>(ep + kt * 32);
          float4 e1 = *reinterpret_cast<const float4*>(ep + kt * 32 + 4);
          float ef[8] = {e0.x, e0.y, e0.z, e0.w, e1.x, e1.y, e1.z, e1.w};
          bf16x8 vh, vl;
#pragma unroll
          for (int j = 0; j < 8; ++j) {
            __hip_bfloat16 hb = __float2bfloat16(ef[j]);
            __hip_bfloat16 lb = __float2bfloat16(ef[j] - __bfloat162float(hb));
            vh[j] = *reinterpret_cast<short*>(&hb);
            vl[j] = *reinterpret_cast<short*>(&lb);
          }
          axh[mt][kt] = vh; axl[mt][kt] = vl;
        }
      }
      f32x4 a2[6];
#pragma unroll
      for (int i = 0; i < 6; ++i) a2[i] = 0.f;
#pragma unroll
      for (int nt = 0; nt < 3; ++nt)
#pragma unroll
        for (int kt = 0; kt < 2; ++kt) {
          MFMA3(a2[0 * 3 + nt], axh[0][kt], axl[0][kt], bxh[nt][kt], bxl[nt][kt]);
          MFMA3(a2[1 * 3 + nt], axh[1][kt], axl[1][kt], bxh[nt][kt], bxl[nt][kt]);
        }
#pragma unroll
      for (int tile = 0; tile < 6; ++tile)
#pragma unroll
        for (int r = 0; r < 4; ++r)
          red[w][tile][(l >> 4) * 4 + r][l & 15] = a2[tile][r];
      __syncthreads();
#pragma unroll
      for (int q = 0; q < 6; ++q) {
        int o = q * 256 + tid;
        int b = o / 48, c = o - b * 48;
        int tile = (b >> 4) * 3 + (c >> 4);
        gib[tp][b][c] += red[0][tile][b & 15][c & 15] + red[1][tile][b & 15][c & 15] +
                         red[2][tile][b & 15][c & 15] + red[3][tile][b & 15][c & 15];
      }
      __syncthreads();
    }
  };

  build_gi(0, hpHi, hpLo);   // hp == 0 initially (buffers zeroed by memset)

#pragma unroll 1
  for (int t = 0; t < S_; ++t) {
    // ---------------- worker step ----------------
    {
      const __hip_bfloat16* hrH = hwHi + (t & 1) * STATE_STRIDE;
      const __hip_bfloat16* hrL = hwLo + (t & 1) * STATE_STRIDE;
      __hip_bfloat16* hwpH = hwHi + ((t & 1) ^ 1) * STATE_STRIDE;
      __hip_bfloat16* hwpL = hwLo + ((t & 1) ^ 1) * STATE_STRIDE;
      bf16x8 ah[2][4], al[2][4];
#pragma unroll
      for (int mt = 0; mt < 2; ++mt)
#pragma unroll
        for (int kt = 0; kt < 4; ++kt) {
          long o = (long)(r0 + mt * 16 + lrow) * 512 + w * 128 + kt * 32 + lk8;
          ld_pair_sc(hrH + o, hrL + o, ah[mt][kt], al[mt][kt]);
        }
      f32x4 acc[6];
#pragma unroll
      for (int i = 0; i < 6; ++i) acc[i] = 0.f;
#pragma unroll
      for (int kt = 0; kt < 4; ++kt)
#pragma unroll
        for (int nt = 0; nt < 3; ++nt) {
          MFMA3(acc[0 * 3 + nt], ah[0][kt], al[0][kt], whh_h[nt][kt], whh_l[nt][kt]);
          MFMA3(acc[1 * 3 + nt], ah[1][kt], al[1][kt], whh_h[nt][kt], whh_l[nt][kt]);
        }
#pragma unroll
      for (int tile = 0; tile < 6; ++tile)
#pragma unroll
        for (int r = 0; r < 4; ++r)
          red[w][tile][(l >> 4) * 4 + r][l & 15] = acc[tile][r];
      __syncthreads();
      int tc = t & 3;
#pragma unroll
      for (int q = 0; q < 2; ++q) {
        int o = tid * 2 + q;
        int b = o >> 4, j = o & 15, mt = b >> 4, rr = b & 15;
        float gr = red[0][mt * 3 + 0][rr][j] + red[1][mt * 3 + 0][rr][j] +
                   red[2][mt * 3 + 0][rr][j] + red[3][mt * 3 + 0][rr][j] + bhh_s[j];
        float gz = red[0][mt * 3 + 1][rr][j] + red[1][mt * 3 + 1][rr][j] +
                   red[2][mt * 3 + 1][rr][j] + red[3][mt * 3 + 1][rr][j] + bhh_s[16 + j];
        float gn = red[0][mt * 3 + 2][rr][j] + red[1][mt * 3 + 2][rr][j] +
                   red[2][mt * 3 + 2][rr][j] + red[3][mt * 3 + 2][rr][j] + bhh_s[32 + j];
        float rg = sigm(gib[tc][b][j] + gr);
        float zg = sigm(gib[tc][b][16 + j] + gz);
        float ng = tanh_f(gib[tc][b][32 + j] + rg * gn);
        float h = hwm[b][j];
        float hn2 = (t < len_s[b]) ? ((1.f - zg) * ng + zg * h) : h;
        hwm[b][j] = hn2;
        st_pair_sc(hwpH, hwpL, (long)(r0 + b) * 512 + hc0 + j, hn2);
      }
      grp_barrier(flagsG, m, ++bar);
    }

    // ---------------- planner (every 4th step) ----------------
    if (((t + 1) & 3) == 0) {
      const __hip_bfloat16* hrH = hwHi + ((t & 1) ^ 1) * STATE_STRIDE;  // post-update hw
      const __hip_bfloat16* hrL = hwLo + ((t & 1) ^ 1) * STATE_STRIDE;
      int c = t >> 2;
      const __hip_bfloat16* hprH = hpHi + (c & 1) * STATE_STRIDE;
      const __hip_bfloat16* hprL = hpLo + (c & 1) * STATE_STRIDE;
      __hip_bfloat16* hpwH = hpHi + ((c & 1) ^ 1) * STATE_STRIDE;
      __hip_bfloat16* hpwL = hpLo + ((c & 1) ^ 1) * STATE_STRIDE;

      // pin = hw @ pin_w.T + pin_b (own 16 cols); Pin streamed (plain, cached)
      {
        bf16x8 ah[2][4], al[2][4];
#pragma unroll
        for (int mt = 0; mt < 2; ++mt)
#pragma unroll
          for (int kt = 0; kt < 4; ++kt) {
            long o = (long)(r0 + mt * 16 + lrow) * 512 + w * 128 + kt * 32 + lk8;
            ld_pair_sc(hrH + o, hrL + o, ah[mt][kt], al[mt][kt]);
          }
        f32x4 pa[2];
        pa[0] = 0.f; pa[1] = 0.f;
#pragma unroll
        for (int kt = 0; kt < 4; ++kt) {
          long o = (long)(hc0 + lrow) * 512 + w * 128 + kt * 32 + lk8;
          bf16x8 bnh = *(const bf16x8*)(PinHi + o);
          bf16x8 bnl = *(const bf16x8*)(PinLo + o);
          MFMA3(pa[0], ah[0][kt], al[0][kt], bnh, bnl);
          MFMA3(pa[1], ah[1][kt], al[1][kt], bnh, bnl);
        }
#pragma unroll
        for (int mt = 0; mt < 2; ++mt)
#pragma unroll
          for (int r = 0; r < 4; ++r)
            red[w][mt][(l >> 4) * 4 + r][l & 15] = pa[mt][r];
        __syncthreads();
#pragma unroll
        for (int q = 0; q < 2; ++q) {
          int o = tid * 2 + q;
          int b = o >> 4, j = o & 15;
          float v = red[0][b >> 4][b & 15][j] + red[1][b >> 4][b & 15][j] +
                    red[2][b >> 4][b & 15][j] + red[3][b >> 4][b & 15][j] + pinb_s[j];
          st_pair_sc(pinHi, pinLo, (long)(r0 + b) * 512 + hc0 + j, v);
        }
        grp_barrier(flagsG, m, ++bar);
      }

      // planner GRU gates
      {
        bf16x8 ah[2][4], al[2][4];
#pragma unroll
        for (int mt = 0; mt < 2; ++mt)
#pragma unroll
          for (int kt = 0; kt < 4; ++kt) {
            long o = (long)(r0 + mt * 16 + lrow) * 512 + w * 128 + kt * 32 + lk8;
            ld_pair_sc(pinHi + o, pinLo + o, ah[mt][kt], al[mt][kt]);
          }
        f32x4 acc[6];
#pragma unroll
        for (int i = 0; i < 6; ++i) acc[i] = 0.f;
#pragma unroll
        for (int nt = 0; nt < 3; ++nt)
#pragma unroll
          for (int kt = 0; kt < 4; ++kt) {
            MFMA3(acc[0 * 3 + nt], ah[0][kt], al[0][kt], wip_h[nt][kt], wip_l[nt][kt]);
            MFMA3(acc[1 * 3 + nt], ah[1][kt], al[1][kt], wip_h[nt][kt], wip_l[nt][kt]);
          }
#pragma unroll
        for (int tile = 0; tile < 6; ++tile)
#pragma unroll
          for (int r = 0; r < 4; ++r)
            red[w][tile][(l >> 4) * 4 + r][l & 15] = acc[tile][r];
        __syncthreads();
#pragma unroll
        for (int q = 0; q < 6; ++q) {
          int o = q * 256 + tid;
          int b = o / 48, cc = o - b * 48;
          int tile = (b >> 4) * 3 + (cc >> 4);
          giP[b][cc] = red[0][tile][b & 15][cc & 15] + red[1][tile][b & 15][cc & 15] +
                       red[2][tile][b & 15][cc & 15] + red[3][tile][b & 15][cc & 15] +
                       bihp_s[cc];
        }
        __syncthreads();
#pragma unroll
        for (int mt = 0; mt < 2; ++mt)
#pragma unroll
          for (int kt = 0; kt < 4; ++kt) {
            long o = (long)(r0 + mt * 16 + lrow) * 512 + w * 128 + kt * 32 + lk8;
            ld_pair_sc(hprH + o, hprL + o, ah[mt][kt], al[mt][kt]);
          }
#pragma unroll
        for (int i = 0; i < 6; ++i) acc[i] = 0.f;
#pragma unroll
        for (int nt = 0; nt < 3; ++nt)
#pragma unroll
          for (int kt = 0; kt < 4; ++kt) {
            MFMA3(acc[0 * 3 + nt], ah[0][kt], al[0][kt], whp_h[nt][kt], whp_l[nt][kt]);
            MFMA3(acc[1 * 3 + nt], ah[1][kt], al[1][kt], whp_h[nt][kt], whp_l[nt][kt]);
          }
#pragma unroll
        for (int tile = 0; tile < 6; ++tile)
#pragma unroll
          for (int r = 0; r < 4; ++r)
            red[w][tile][(l >> 4) * 4 + r][l & 15] = acc[tile][r];
        __syncthreads();
#pragma unroll
        for (int q = 0; q < 2; ++q) {
          int o = tid * 2 + q;
          int b = o >> 4, j = o & 15, mt = b >> 4, rr = b & 15;
          float gr = red[0][mt * 3 + 0][rr][j] + red[1][mt * 3 + 0][rr][j] +
                     red[2][mt * 3 + 0][rr][j] + red[3][mt * 3 + 0][rr][j] + bhhp_s[j];
          float gz = red[0][mt * 3 + 1][rr][j] + red[1][mt * 3 + 1][rr][j] +
                     red[2][mt * 3 + 1][rr][j] + red[3][mt * 3 + 1][rr][j] + bhhp_s[16 + j];
          float gn = red[0][mt * 3 + 2][rr][j] + red[1][mt * 3 + 2][rr][j] +
                     red[2][mt * 3 + 2][rr][j] + red[3][mt * 3 + 2][rr][j] + bhhp_s[32 + j];
          float rg = sigm(giP[b][j] + gr);
          float zg = sigm(giP[b][16 + j] + gz);
          float ng = tanh_f(giP[b][32 + j] + rg * gn);
          float h = hpm[b][j];
          float hn2 = (t < len_s[b]) ? ((1.f - zg) * ng + zg * h) : h;
          hpm[b][j] = hn2;
          st_pair_sc(hpwH, hpwL, (long)(r0 + b) * 512 + hc0 + j, hn2);
        }
        grp_barrier(flagsG, m, ++bar);
      }

      if (t + 1 < S_) build_gi(t + 1, hpwH, hpwL);
    }
  }

  // fp32 finals for the head (plain stores; next dispatch sees them)
#pragma unroll
  for (int q = 0; q < 2; ++q) {
    int o = tid * 2 + q;
    int b = o >> 4, j = o & 15;
    hw_f[(long)(r0 + b) * 512 + hc0 + j] = hwm[b][j];
    hp_f[(long)(r0 + b) * 512 + hc0 + j] = hpm[b][j];
  }
}

// fused = tanh([hw,hp] @ fus_w.T + fus_b); h = relu(fused @ h1_w.T + h1_b);
// out = h @ h2_w.T + h2_b.   One block per batch row, fp32.
__global__ __launch_bounds__(256) void head_k(
    const float* __restrict__ hwf, const float* __restrict__ hpf,
    const float* __restrict__ fw, const float* __restrict__ fb,
    const float* __restrict__ w1, const float* __restrict__ b1,
    const float* __restrict__ w2, const float* __restrict__ b2,
    float* __restrict__ out)
{
  int b = blockIdx.x;
  int tid = threadIdx.x;
  __shared__ __align__(16) float xin[1024];
  __shared__ __align__(16) float fused[512];
  __shared__ __align__(16) float hh[512];
  for (int i = tid; i < 512; i += 256) {
    xin[i] = hwf[b * 512 + i];
    xin[512 + i] = hpf[b * 512 + i];
  }
  __syncthreads();
  for (int o = tid; o < 512; o += 256) {
    const float4* wr = reinterpret_cast<const float4*>(fw + o * 1024);
    const float4* xr = reinterpret_cast<const float4*>(xin);
    float acc = fb[o];
    for (int k = 0; k < 256; ++k) {
      float4 wv = wr[k], xv = xr[k];
      acc += wv.x * xv.x + wv.y * xv.y + wv.z * xv.z + wv.w * xv.w;
    }
    fused[o] = tanhf(acc);
  }
  __syncthreads();
  for (int o = tid; o < 512; o += 256) {
    const float4* wr = reinterpret_cast<const float4*>(w1 + o * 512);
    const float4* xr = reinterpret_cast<const float4*>(fused);
    float acc = b1[o];
    for (int k = 0; k < 128; ++k) {
      float4 wv = wr[k], xv = xr[k];
      acc += wv.x * xv.x + wv.y * xv.y + wv.z * xv.z + wv.w * xv.w;
    }
    hh[o] = fmaxf(acc, 0.f);
  }
  __syncthreads();
  if (tid < 10) {
    const float4* wr = reinterpret_cast<const float4*>(w2 + tid * 512);
    const float4* xr = reinterpret_cast<const float4*>(hh);
    float acc = b2[tid];
    for (int k = 0; k < 128; ++k) {
      float4 wv = wr[k], xv = xr[k];
      acc += wv.x * xv.x + wv.y * xv.y + wv.z * xv.z + wv.w * xv.w;
    }
    out[b * 10 + tid] = acc;
  }
}

extern "C" void kernel_launch(void* const* d_in, const int* in_sizes, int n_in,
                              void* d_out, int out_size, void* d_ws, size_t ws_size,
                              hipStream_t stream) {
  const int*   ids    = (const int*)d_in[0];
  const int*   lens   = (const int*)d_in[1];
  const float* emb    = (const float*)d_in[2];
  const float* w_ih_w = (const float*)d_in[3];
  const float* w_hh_w = (const float*)d_in[4];
  const float* b_ih_w = (const float*)d_in[5];
  const float* b_hh_w = (const float*)d_in[6];
  const float* pin_w  = (const float*)d_in[7];
  const float* pin_b  = (const float*)d_in[8];
  const float* w_ih_p = (const float*)d_in[9];
  const float* w_hh_p = (const float*)d_in[10];
  const float* b_ih_p = (const float*)d_in[11];
  const float* b_hh_p = (const float*)d_in[12];
  const float* fus_w  = (const float*)d_in[13];
  const float* fus_b  = (const float*)d_in[14];
  const float* h1_w   = (const float*)d_in[15];
  const float* h1_b   = (const float*)d_in[16];
  const float* h2_w   = (const float*)d_in[17];
  const float* h2_b   = (const float*)d_in[18];
  float* out = (float*)d_out;

  char* ws = (char*)d_ws;
  size_t off = 0;
  auto alloc = [&](size_t bytes) -> void* {
    void* p = ws + off;
    off += (bytes + 255) & ~(size_t)255;
    return p;
  };
  unsigned*        flags = (unsigned*)alloc(8 * 512 * sizeof(unsigned));
  __hip_bfloat16*  hwHi = (__hip_bfloat16*)alloc(2 * STATE_STRIDE * 2);
  __hip_bfloat16*  hwLo = (__hip_bfloat16*)alloc(2 * STATE_STRIDE * 2);
  __hip_bfloat16*  hpHi = (__hip_bfloat16*)alloc(2 * STATE_STRIDE * 2);
  __hip_bfloat16*  hpLo = (__hip_bfloat16*)alloc(2 * STATE_STRIDE * 2);
  size_t zero_bytes = off;              // flags + hw/hp pairs must start at 0
  __hip_bfloat16*  pinHi = (__hip_bfloat16*)alloc(STATE_STRIDE * 2);
  __hip_bfloat16*  pinLo = (__hip_bfloat16*)alloc(STATE_STRIDE * 2);
  float*           hw_f  = (float*)alloc(STATE_STRIDE * 4);
  float*           hp_f  = (float*)alloc(STATE_STRIDE * 4);
  __hip_bfloat16*  WihHi = (__hip_bfloat16*)alloc((size_t)1536 * 768 * 2);
  __hip_bfloat16*  WihLo = (__hip_bfloat16*)alloc((size_t)1536 * 768 * 2);
  __hip_bfloat16*  WhhHi = (__hip_bfloat16*)alloc((size_t)1536 * 512 * 2);
  __hip_bfloat16*  WhhLo = (__hip_bfloat16*)alloc((size_t)1536 * 512 * 2);
  __hip_bfloat16*  PinHi = (__hip_bfloat16*)alloc((size_t)512 * 512 * 2);
  __hip_bfloat16*  PinLo = (__hip_bfloat16*)alloc((size_t)512 * 512 * 2);
  __hip_bfloat16*  WipHi = (__hip_bfloat16*)alloc((size_t)1536 * 512 * 2);
  __hip_bfloat16*  WipLo = (__hip_bfloat16*)alloc((size_t)1536 * 512 * 2);
  __hip_bfloat16*  WhpHi = (__hip_bfloat16*)alloc((size_t)1536 * 512 * 2);
  __hip_bfloat16*  WhpLo = (__hip_bfloat16*)alloc((size_t)1536 * 512 * 2);

  (void)hipMemsetAsync(d_ws, 0, zero_bytes, stream);
  split_hilo<<<1024, 256, 0, stream>>>(w_ih_w, WihHi, WihLo, 1536 * 768);
  split_hilo<<<1024, 256, 0, stream>>>(w_hh_w, WhhHi, WhhLo, 1536 * 512);
  split_hilo<<<512, 256, 0, stream>>>(pin_w, PinHi, PinLo, 512 * 512);
  split_hilo<<<1024, 256, 0, stream>>>(w_ih_p, WipHi, WipLo, 1536 * 512);
  split_hilo<<<1024, 256, 0, stream>>>(w_hh_p, WhpHi, WhpLo, 1536 * 512);

  // Plain launch — all 256 blocks co-resident at 1 block/CU (256 CUs).
  hgru_main<<<dim3(256), dim3(256), 0, stream>>>(
      ids, lens, emb, b_ih_w, b_hh_w, pin_b, b_ih_p, b_hh_p,
      WihHi, WihLo, WhhHi, WhhLo, PinHi, PinLo, WipHi, WipLo, WhpHi, WhpLo,
      hwHi, hwLo, hpHi, hpLo, pinHi, pinLo, hw_f, hp_f, flags);

  head_k<<<256, 256, 0, stream>>>(hw_f, hp_f, fus_w, fus_b, h1_w, h1_b, h2_w, h2_b, out);
}